// Round 12
// baseline (278.023 us; speedup 1.0000x reference)
//
#include <hip/hip_runtime.h>

#define D_FEAT 256
#define NEG_SLOPE 0.2f
#define MAXBINS 512
#define SENT 0xFFFFFFFFu

__device__ __forceinline__ unsigned fmap(float f) {
    unsigned u = __float_as_uint(f);
    return (u & 0x80000000u) ? ~u : (u | 0x80000000u);
}
__device__ __forceinline__ float funmap(unsigned u) {
    return __uint_as_float((u & 0x80000000u) ? (u ^ 0x80000000u) : ~u);
}
__device__ __forceinline__ float dot4(float4 v, float4 w) {
    return v.x * w.x + v.y * w.y + v.z * w.z + v.w * w.w;
}

// sc layout: [0] gmax_u  [1] gsum(f32)  [2] argmin  [3] M(f32)
//            [4..7] fallback AB extrema  [8] pool done-counter  [9] hist done-counter

// ---------------- sorted-path preamble: dots+ab, 4 nodes/wave ----------------
__global__ void k_pre(const float* __restrict__ x, const float* __restrict__ w_l,
                      const float* __restrict__ w_r, const float* __restrict__ pos,
                      const float* __restrict__ w_e,
                      float2* __restrict__ sA, float* __restrict__ Bv,
                      float4* __restrict__ gABpart, unsigned* __restrict__ stampW,
                      unsigned* __restrict__ gHist, unsigned* __restrict__ sc,
                      int n, int nW) {
    int blk = blockIdx.x, tid = threadIdx.x;
    int gid = blk * 256 + tid;
    if (gid < nW) stampW[gid] = 0xFFFFFFFFu;
    if (blk == 0) {
        if (tid < MAXBINS) gHist[tid] = 0u;
        if (tid + 256 < MAXBINS) gHist[tid + 256] = 0u;
        if (tid == 0) { sc[8] = 0u; sc[9] = 0u; }
    }
    int w = tid >> 6, lane = tid & 63;
    int node0 = blk * 16 + w * 4;
    float4 al = ((const float4*)w_l)[lane];
    float4 bl = ((const float4*)w_r)[lane];
    float sl0 = 0.f, sl1 = 0.f, sl2 = 0.f, sl3 = 0.f;
    float sr0 = 0.f, sr1 = 0.f, sr2 = 0.f, sr3 = 0.f;
    if (node0 + 3 < n) {
        float4 v0 = ((const float4*)(x + (size_t)node0 * D_FEAT))[lane];
        float4 v1 = ((const float4*)(x + (size_t)(node0 + 1) * D_FEAT))[lane];
        float4 v2 = ((const float4*)(x + (size_t)(node0 + 2) * D_FEAT))[lane];
        float4 v3 = ((const float4*)(x + (size_t)(node0 + 3) * D_FEAT))[lane];
        sl0 = dot4(v0, al); sr0 = dot4(v0, bl);
        sl1 = dot4(v1, al); sr1 = dot4(v1, bl);
        sl2 = dot4(v2, al); sr2 = dot4(v2, bl);
        sl3 = dot4(v3, al); sr3 = dot4(v3, bl);
    } else if (node0 < n) {
        {
            float4 v = ((const float4*)(x + (size_t)node0 * D_FEAT))[lane];
            sl0 = dot4(v, al); sr0 = dot4(v, bl);
        }
        if (node0 + 1 < n) {
            float4 v = ((const float4*)(x + (size_t)(node0 + 1) * D_FEAT))[lane];
            sl1 = dot4(v, al); sr1 = dot4(v, bl);
        }
        if (node0 + 2 < n) {
            float4 v = ((const float4*)(x + (size_t)(node0 + 2) * D_FEAT))[lane];
            sl2 = dot4(v, al); sr2 = dot4(v, bl);
        }
    }
    #pragma unroll
    for (int o = 32; o; o >>= 1) {
        sl0 += __shfl_xor(sl0, o); sr0 += __shfl_xor(sr0, o);
        sl1 += __shfl_xor(sl1, o); sr1 += __shfl_xor(sr1, o);
        sl2 += __shfl_xor(sl2, o); sr2 += __shfl_xor(sr2, o);
        sl3 += __shfl_xor(sl3, o); sr3 += __shfl_xor(sr3, o);
    }
    float amax = -INFINITY, bmaxv = -INFINITY, amin = INFINITY, bminv = INFINITY;
    int node = node0 + lane;
    if (lane < 4 && node < n) {
        float slv = (lane == 0) ? sl0 : (lane == 1) ? sl1 : (lane == 2) ? sl2 : sl3;
        float srv = (lane == 0) ? sr0 : (lane == 1) ? sr1 : (lane == 2) ? sr2 : sr3;
        float p = pos[3 * node] * w_e[0] + pos[3 * node + 1] * w_e[1]
                + pos[3 * node + 2] * w_e[2];
        float a = slv - p, b = srv + p;
        sA[node] = make_float2(a, slv);
        Bv[node] = b;
        amax = a; amin = a; bmaxv = b; bminv = b;
    }
    #pragma unroll
    for (int o = 1; o < 4; o <<= 1) {
        amax = fmaxf(amax, __shfl_xor(amax, o));
        bmaxv = fmaxf(bmaxv, __shfl_xor(bmaxv, o));
        amin = fminf(amin, __shfl_xor(amin, o));
        bminv = fminf(bminv, __shfl_xor(bminv, o));
    }
    __shared__ float s4[4][4];
    if (lane == 0) { s4[w][0] = amax; s4[w][1] = bmaxv; s4[w][2] = amin; s4[w][3] = bminv; }
    __syncthreads();
    if (tid == 0) {
        float AM = s4[0][0], BM = s4[0][1], Am = s4[0][2], Bm = s4[0][3];
        #pragma unroll
        for (int k = 1; k < 4; ++k) {
            AM = fmaxf(AM, s4[k][0]); BM = fmaxf(BM, s4[k][1]);
            Am = fminf(Am, s4[k][2]); Bm = fminf(Bm, s4[k][3]);
        }
        gABpart[blk] = make_float4(AM, BM, Am, Bm);
    }
}

// 512 blocks: dst-bin histogram; last-arriving block (done-counter sc[9]) then
// reduces gABpart -> M, inits sc[0..2], and scans padded capacities -> gBase/gCursor.
__global__ void k_hist(const int4* __restrict__ dst4, int E4, int nbins,
                       unsigned* __restrict__ gHist,
                       const float4* __restrict__ gABpart, int nAB,
                       unsigned* __restrict__ gBase, unsigned* __restrict__ gCursor,
                       int nBlk, unsigned* sc, const float* __restrict__ att) {
    __shared__ unsigned h[MAXBINS];
    int tid = threadIdx.x;
    for (int b = tid; b < nbins; b += blockDim.x) h[b] = 0u;
    __syncthreads();
    int stride = gridDim.x * blockDim.x;
    for (int i = blockIdx.x * blockDim.x + tid; i < E4; i += stride) {
        int4 d = dst4[i];
        atomicAdd(&h[d.x >> 8], 1u);
        atomicAdd(&h[d.y >> 8], 1u);
        atomicAdd(&h[d.z >> 8], 1u);
        atomicAdd(&h[d.w >> 8], 1u);
    }
    __syncthreads();
    for (int b = tid; b < nbins; b += blockDim.x)
        if (h[b]) atomicAdd(&gHist[b], h[b]);
    __threadfence();
    __shared__ unsigned done;
    if (tid == 0) done = atomicAdd(&sc[9], 1u);
    __syncthreads();
    if (done != (unsigned)(gridDim.x - 1)) return;
    __threadfence();
    // ---- former k_scan2 body (runs in the last block only) ----
    float AM = -INFINITY, BM = -INFINITY, Am = INFINITY, Bm = INFINITY;
    for (int i = tid; i < nAB; i += 256) {
        float4 v = gABpart[i];
        AM = fmaxf(AM, v.x); BM = fmaxf(BM, v.y);
        Am = fminf(Am, v.z); Bm = fminf(Bm, v.w);
    }
    #pragma unroll
    for (int o = 32; o; o >>= 1) {
        AM = fmaxf(AM, __shfl_xor(AM, o)); BM = fmaxf(BM, __shfl_xor(BM, o));
        Am = fminf(Am, __shfl_xor(Am, o)); Bm = fminf(Bm, __shfl_xor(Bm, o));
    }
    __shared__ float s4[4][4];
    int w = tid >> 6, lane = tid & 63;
    if (lane == 0) { s4[w][0] = AM; s4[w][1] = BM; s4[w][2] = Am; s4[w][3] = Bm; }
    __syncthreads();
    if (tid == 0) {
        float am = s4[0][0], bm = s4[0][1], an = s4[0][2], bn = s4[0][3];
        #pragma unroll
        for (int k = 1; k < 4; ++k) {
            am = fmaxf(am, s4[k][0]); bm = fmaxf(bm, s4[k][1]);
            an = fminf(an, s4[k][2]); bn = fminf(bn, s4[k][3]);
        }
        float at = att[0];
        float z = (at >= 0.f) ? (am + bm) : (an + bn);
        float lz = (z >= 0.f) ? z : NEG_SLOPE * z;
        ((float*)sc)[3] = lz * at;
        sc[0] = 0u; ((float*)sc)[1] = 0.f; sc[2] = 0xFFFFFFFFu;
    }
    __syncthreads();
    if (tid < 64) {
        unsigned padw = 15u * (unsigned)nBlk;
        unsigned carry = 0;
        for (int b0 = 0; b0 < nbins; b0 += 64) {
            int b = b0 + tid;
            unsigned v = (b < nbins) ? ((gHist[b] + padw + 15u) & ~15u) : 0u;
            unsigned inc = v;
            #pragma unroll
            for (int o = 1; o < 64; o <<= 1) {
                unsigned t = __shfl_up(inc, o);
                if (tid >= o) inc += t;
            }
            unsigned excl = inc - v + carry;
            if (b < nbins) { gBase[b] = excl; gCursor[b] = excl; }
            carry += __shfl(inc, 63);
        }
    }
}

// 512 threads, 8192 edges/block. LDS hist -> 16-word-aligned runs ->
// scatter 4B words  src | (dst&255)<<17; pad runs with SENT.
__global__ void k_scatter(const int4* __restrict__ src4, const int4* __restrict__ dst4,
                          unsigned* __restrict__ gCursor, unsigned* __restrict__ recs,
                          int E4, int nbins) {
    __shared__ unsigned h[MAXBINS];
    __shared__ unsigned base[MAXBINS];
    for (int b = threadIdx.x; b < nbins; b += 512) h[b] = 0u;
    __syncthreads();
    int b4 = blockIdx.x * 2048;
    #pragma unroll
    for (int g = 0; g < 4; ++g) {
        int idx = b4 + g * 512 + threadIdx.x;
        if (idx < E4) {
            int4 d = dst4[idx];
            atomicAdd(&h[d.x >> 8], 1u);
            atomicAdd(&h[d.y >> 8], 1u);
            atomicAdd(&h[d.z >> 8], 1u);
            atomicAdd(&h[d.w >> 8], 1u);
        }
    }
    __syncthreads();
    for (int b = threadIdx.x; b < nbins; b += 512) {
        unsigned c = h[b];
        h[b] = 0u;
        base[b] = c ? atomicAdd(&gCursor[b], (c + 15u) & ~15u) : 0u;
    }
    __syncthreads();
    #pragma unroll
    for (int g = 0; g < 4; ++g) {
        int idx = b4 + g * 512 + threadIdx.x;
        if (idx < E4) {
            int4 sv = src4[idx];
            int4 dv = dst4[idx];
            int ss[4] = { sv.x, sv.y, sv.z, sv.w };
            int dd[4] = { dv.x, dv.y, dv.z, dv.w };
            #pragma unroll
            for (int j = 0; j < 4; ++j) {
                int d_ = dd[j];
                int bin = d_ >> 8;
                unsigned off = atomicAdd(&h[bin], 1u);
                recs[base[bin] + off] = (unsigned)ss[j] | ((unsigned)(d_ & 255) << 17);
            }
        }
    }
    __syncthreads();
    for (int b = threadIdx.x; b < nbins; b += 512) {
        unsigned c = h[b];
        unsigned pc = (c + 15u) & ~15u;
        for (unsigned k = c; k < pc; ++k) recs[base[b] + k] = SENT;
    }
}

// One block per bin: uint4 record loads (quad-SENT skip: pad is a suffix of each
// 16-word-aligned run, so x==SENT => whole quad is pad), recompute ex, LDS
// accumulate, fused logits + global max.
__global__ void k_binsum(const uint4* __restrict__ recs4, const unsigned* __restrict__ gBase,
                         const unsigned* __restrict__ gCursor,
                         const float2* __restrict__ sA, const float* __restrict__ Bv,
                         const float* __restrict__ att, const float* __restrict__ bias,
                         float* __restrict__ logits, unsigned* sc, int n) {
    __shared__ float accx[256];
    __shared__ float accy[256];
    __shared__ float Bb[256];
    int b = blockIdx.x;
    int tid = threadIdx.x;
    int node0 = b << 8;
    accx[tid] = 0.f; accy[tid] = 0.f;
    Bb[tid] = (node0 + tid < n) ? Bv[node0 + tid] : 0.f;
    __syncthreads();
    const float at = att[0];
    const float M = ((const float*)sc)[3];
    unsigned q0 = gBase[b] >> 2, q1 = gCursor[b] >> 2;
    for (unsigned i = q0 + tid; i < q1; i += 256u) {
        uint4 r4 = recs4[i];
        if (r4.x == SENT) continue;            // whole quad is pad
        unsigned ws[4] = { r4.x, r4.y, r4.z, r4.w };
        #pragma unroll
        for (int j = 0; j < 4; ++j) {
            unsigned wv = ws[j];
            if (wv == SENT) continue;
            int sidx = (int)(wv & 0x1FFFFu);
            int loc  = (int)(wv >> 17);
            float2 sa = sA[sidx];
            float msg = sa.x + Bb[loc];
            float lr = (msg >= 0.f) ? msg : NEG_SLOPE * msg;
            float e = expf(lr * at - M);
            atomicAdd(&accx[loc], e);
            atomicAdd(&accy[loc], e * sa.y);
        }
    }
    __syncthreads();
    int node = node0 + tid;
    float lg = -INFINITY;
    if (node < n) {
        lg = accy[tid] / (accx[tid] + 1e-38f) + bias[0];
        logits[node] = lg;
    }
    unsigned mu = fmap(lg);
    #pragma unroll
    for (int o = 32; o; o >>= 1) { unsigned t = __shfl_xor(mu, o); mu = (t > mu) ? t : mu; }
    __shared__ unsigned wm[4];
    int w_ = tid >> 6, l = tid & 63;
    if (l == 0) wm[w_] = mu;
    __syncthreads();
    if (tid == 0) {
        unsigned m = wm[0];
        #pragma unroll
        for (int k = 1; k < 4; ++k) m = (wm[k] > m) ? wm[k] : m;
        atomicMax(&sc[0], m);
    }
}

// ---------------- tail kernels ----------------

// sum of exp(l-gmax) + first argmax; stores ex back into logits (logits dead after)
__global__ void k_sumarg(float* __restrict__ logits, unsigned* sc, int n) {
    int i = blockIdx.x * blockDim.x + threadIdx.x;
    unsigned gmax_u = sc[0];
    float gmax = funmap(gmax_u);
    float ex = 0.f;
    if (i < n) {
        float lg = logits[i];
        ex = expf(lg - gmax);
        if (fmap(lg) == gmax_u) atomicMin(&sc[2], (unsigned)i);
        logits[i] = ex;
    }
    #pragma unroll
    for (int o = 32; o; o >>= 1) ex += __shfl_xor(ex, o);
    if ((threadIdx.x & 63) == 0) atomicAdd((float*)&sc[1], ex);
}

// out = stored_ex / gsum ; seed BFS stamp at argmax
__global__ void k_score(const float* __restrict__ logits, const unsigned* __restrict__ sc,
                        float* __restrict__ out, unsigned char* stamp, int n) {
    int i = blockIdx.x * blockDim.x + threadIdx.x;
    if (i >= n) return;
    float gsum = ((const float*)sc)[1];
    out[i] = logits[i] / gsum;
    if (i == (int)sc[2]) stamp[i] = 0;
}

// In-place timestamp BFS pass t (frontier-growing passes 1..4).
__global__ void k_bfs_stamp(const int4* __restrict__ src4, const int4* __restrict__ dst4,
                            unsigned char* __restrict__ stamp, int E4, int t) {
    int i = blockIdx.x * blockDim.x + threadIdx.x;
    if (i >= E4) return;
    int4 s = src4[i];
    unsigned char th = (unsigned char)t;
    bool h0 = stamp[s.x] < th;
    bool h1 = stamp[s.y] < th;
    bool h2 = stamp[s.z] < th;
    bool h3 = stamp[s.w] < th;
    if (!(h0 | h1 | h2 | h3)) return;
    int4 d = dst4[i];
    if (h0 && stamp[d.x] > th) stamp[d.x] = th;
    if (h1 && stamp[d.y] > th) stamp[d.y] = th;
    if (h2 && stamp[d.z] > th) stamp[d.z] = th;
    if (h3 && stamp[d.w] > th) stamp[d.w] = th;
}

// Saturated-frontier BFS pass over dst-binned records: block b owns nodes
// [b*256,(b+1)*256); returns immediately unless one of its nodes is still
// unreached (by pass 5 that's ~0.01% of blocks). Writes are block-local.
__global__ void k_bfs_rec(const uint4* __restrict__ recs4, const unsigned* __restrict__ gBase,
                          const unsigned* __restrict__ gCursor,
                          unsigned char* __restrict__ stamp, int n, int t) {
    __shared__ unsigned char st[256];
    __shared__ unsigned char mark[256];
    __shared__ unsigned char wn[4];
    int b = blockIdx.x;
    int tid = threadIdx.x;
    int node = (b << 8) + tid;
    unsigned char th = (unsigned char)t;
    unsigned char s = (node < n) ? stamp[node] : (unsigned char)0;
    st[tid] = s; mark[tid] = 0;
    unsigned long long ball = __ballot(s > th);
    if ((tid & 63) == 0) wn[tid >> 6] = (ball != 0ull) ? 1 : 0;
    __syncthreads();
    if (!(wn[0] | wn[1] | wn[2] | wn[3])) return;
    unsigned q0 = gBase[b] >> 2, q1 = gCursor[b] >> 2;
    for (unsigned i = q0 + tid; i < q1; i += 256u) {
        uint4 r4 = recs4[i];
        if (r4.x == SENT) continue;
        unsigned ws[4] = { r4.x, r4.y, r4.z, r4.w };
        #pragma unroll
        for (int j = 0; j < 4; ++j) {
            unsigned wv = ws[j];
            if (wv == SENT) continue;
            int loc = (int)(wv >> 17);
            if (st[loc] > th) {
                if (stamp[wv & 0x1FFFFu] < th) mark[loc] = 1;
            }
        }
    }
    __syncthreads();
    if (mark[tid] && node < n && st[tid] > th) stamp[node] = th;
}

// pool stage 1: conditional float4 loads, wave-uniform stamp skip
__global__ void k_pool1(const float* __restrict__ x, const unsigned char* __restrict__ stamp,
                        float4* __restrict__ partial, int n) {
    int sub = threadIdx.x >> 6;
    int lane = threadIdx.x & 63;
    float4 m = make_float4(-INFINITY, -INFINITY, -INFINITY, -INFINITY);
    int stride = gridDim.x * 4;
    for (int node = blockIdx.x * 4 + sub; node < n; node += stride) {
        if (stamp[node] != 0xFF) {
            float4 v = ((const float4*)(x + (size_t)node * D_FEAT))[lane];
            m.x = fmaxf(m.x, v.x); m.y = fmaxf(m.y, v.y);
            m.z = fmaxf(m.z, v.z); m.w = fmaxf(m.w, v.w);
        }
    }
    __shared__ float4 red[256];
    red[threadIdx.x] = m;
    __syncthreads();
    if (sub == 0) {
        float4 a = red[lane], b = red[64 + lane], c = red[128 + lane], d = red[192 + lane];
        a.x = fmaxf(fmaxf(a.x, b.x), fmaxf(c.x, d.x));
        a.y = fmaxf(fmaxf(a.y, b.y), fmaxf(c.y, d.y));
        a.z = fmaxf(fmaxf(a.z, b.z), fmaxf(c.z, d.z));
        a.w = fmaxf(fmaxf(a.w, b.w), fmaxf(c.w, d.w));
        partial[(size_t)blockIdx.x * 64 + lane] = a;
    }
}

// pool stage 2: 16 blocks reduce partial rows -> partial2; last block
// (done-counter sc[8]) reduces 16 rows straight into out[n..n+255].
__global__ void k_pool2g(const float4* __restrict__ partial, int nblk1,
                         float4* __restrict__ partial2, unsigned* sc,
                         float* __restrict__ out, int n) {
    int sub = threadIdx.x >> 6;
    int lane = threadIdx.x & 63;
    int chunk = (nblk1 + gridDim.x - 1) / gridDim.x;
    int b0 = blockIdx.x * chunk;
    int b1 = min(b0 + chunk, nblk1);
    float4 m = make_float4(-INFINITY, -INFINITY, -INFINITY, -INFINITY);
    for (int b = b0 + sub; b < b1; b += 4) {
        float4 v = partial[(size_t)b * 64 + lane];
        m.x = fmaxf(m.x, v.x); m.y = fmaxf(m.y, v.y);
        m.z = fmaxf(m.z, v.z); m.w = fmaxf(m.w, v.w);
    }
    __shared__ float4 red[256];
    red[threadIdx.x] = m;
    __syncthreads();
    if (sub == 0) {
        float4 a = red[lane], b = red[64 + lane], c = red[128 + lane], d = red[192 + lane];
        a.x = fmaxf(fmaxf(a.x, b.x), fmaxf(c.x, d.x));
        a.y = fmaxf(fmaxf(a.y, b.y), fmaxf(c.y, d.y));
        a.z = fmaxf(fmaxf(a.z, b.z), fmaxf(c.z, d.z));
        a.w = fmaxf(fmaxf(a.w, b.w), fmaxf(c.w, d.w));
        partial2[(size_t)blockIdx.x * 64 + lane] = a;
    }
    __threadfence();
    __shared__ unsigned done;
    if (threadIdx.x == 0) done = atomicAdd(&sc[8], 1u);
    __syncthreads();
    if (done != (unsigned)(gridDim.x - 1)) return;
    __threadfence();
    float4 m2 = make_float4(-INFINITY, -INFINITY, -INFINITY, -INFINITY);
    for (int r = sub; r < (int)gridDim.x; r += 4) {
        float4 v = partial2[(size_t)r * 64 + lane];
        m2.x = fmaxf(m2.x, v.x); m2.y = fmaxf(m2.y, v.y);
        m2.z = fmaxf(m2.z, v.z); m2.w = fmaxf(m2.w, v.w);
    }
    __syncthreads();
    red[threadIdx.x] = m2;
    __syncthreads();
    if (sub == 0) {
        float4 a = red[lane], b = red[64 + lane], c = red[128 + lane], d = red[192 + lane];
        a.x = fmaxf(fmaxf(a.x, b.x), fmaxf(c.x, d.x));
        a.y = fmaxf(fmaxf(a.y, b.y), fmaxf(c.y, d.y));
        a.z = fmaxf(fmaxf(a.z, b.z), fmaxf(c.z, d.z));
        a.w = fmaxf(fmaxf(a.w, b.w), fmaxf(c.w, d.w));
        out[n + 4 * lane + 0] = a.x;
        out[n + 4 * lane + 1] = a.y;
        out[n + 4 * lane + 2] = a.z;
        out[n + 4 * lane + 3] = a.w;
    }
}

// ---------------- fallback (atomic) path kernels ----------------

__global__ void k_init(float2* NS, unsigned* stampW, int nW, unsigned* pooled_u,
                       unsigned* sc, int n) {
    int i = blockIdx.x * blockDim.x + threadIdx.x;
    if (i < n) NS[i] = make_float2(0.f, 0.f);
    if (i < nW) stampW[i] = 0xFFFFFFFFu;
    if (i < D_FEAT) pooled_u[i] = 0u;
    if (i == 0) {
        sc[0] = 0u; ((float*)sc)[1] = 0.f; sc[2] = 0xFFFFFFFFu;
        sc[4] = 0u; sc[5] = 0u; sc[6] = 0xFFFFFFFFu; sc[7] = 0xFFFFFFFFu;
    }
}

__global__ void k_dots(const float* __restrict__ x, const float* __restrict__ w_l,
                       const float* __restrict__ w_r, float* __restrict__ xl,
                       float* __restrict__ xr, int n) {
    int wave = (int)((blockIdx.x * blockDim.x + threadIdx.x) >> 6);
    int lane = threadIdx.x & 63;
    if (wave >= n) return;
    const float4* xv = (const float4*)(x + (size_t)wave * D_FEAT);
    float4 v = xv[lane];
    float4 a = ((const float4*)w_l)[lane];
    float4 b = ((const float4*)w_r)[lane];
    float sl = dot4(v, a);
    float sr = dot4(v, b);
    #pragma unroll
    for (int o = 32; o; o >>= 1) { sl += __shfl_xor(sl, o); sr += __shfl_xor(sr, o); }
    if (lane == 0) { xl[wave] = sl; xr[wave] = sr; }
}

__global__ void k_ab(const float* __restrict__ xl, const float* __restrict__ xr,
                     const float* __restrict__ pos, const float* __restrict__ w_e,
                     float2* __restrict__ sA, float* __restrict__ B,
                     unsigned* sc, int n) {
    int i = blockIdx.x * blockDim.x + threadIdx.x;
    float amax, amin, bmax, bmin;
    if (i < n) {
        float p = pos[3 * i] * w_e[0] + pos[3 * i + 1] * w_e[1] + pos[3 * i + 2] * w_e[2];
        float xli = xl[i];
        float a = xli - p;
        float b = xr[i] + p;
        sA[i] = make_float2(a, xli);
        B[i] = b;
        amax = amin = a; bmax = bmin = b;
    } else {
        amax = bmax = -INFINITY; amin = bmin = INFINITY;
    }
    #pragma unroll
    for (int o = 32; o; o >>= 1) {
        amax = fmaxf(amax, __shfl_xor(amax, o));
        bmax = fmaxf(bmax, __shfl_xor(bmax, o));
        amin = fminf(amin, __shfl_xor(amin, o));
        bmin = fminf(bmin, __shfl_xor(bmin, o));
    }
    __shared__ float s4[4][4];
    int w = threadIdx.x >> 6, l = threadIdx.x & 63;
    if (l == 0) { s4[w][0] = amax; s4[w][1] = bmax; s4[w][2] = amin; s4[w][3] = bmin; }
    __syncthreads();
    if (threadIdx.x == 0) {
        float AM = s4[0][0], BM = s4[0][1], Am = s4[0][2], Bm = s4[0][3];
        #pragma unroll
        for (int k = 1; k < 4; ++k) {
            AM = fmaxf(AM, s4[k][0]); BM = fmaxf(BM, s4[k][1]);
            Am = fminf(Am, s4[k][2]); Bm = fminf(Bm, s4[k][3]);
        }
        atomicMax(&sc[4], fmap(AM)); atomicMax(&sc[5], fmap(BM));
        atomicMin(&sc[6], fmap(Am)); atomicMin(&sc[7], fmap(Bm));
    }
}

__global__ void k_scanM(unsigned* sc, const float* __restrict__ att) {
    if (threadIdx.x == 0) {
        float at = att[0];
        float z = (at >= 0.f) ? (funmap(sc[4]) + funmap(sc[5]))
                              : (funmap(sc[6]) + funmap(sc[7]));
        float lz = (z >= 0.f) ? z : NEG_SLOPE * z;
        ((float*)sc)[3] = lz * at;
        sc[0] = 0u; ((float*)sc)[1] = 0.f; sc[2] = 0xFFFFFFFFu;
    }
}

__global__ void k_edge_sum(const int* __restrict__ src, const int* __restrict__ dst,
                           const float2* __restrict__ sA, const float* __restrict__ B,
                           const float* __restrict__ att, const unsigned* __restrict__ sc,
                           float2* NS, int E) {
    int i = blockIdx.x * blockDim.x + threadIdx.x;
    if (i >= E) return;
    int s = src[i], d = dst[i];
    float2 sa = sA[s];
    float msg = sa.x + B[d];
    float lr = (msg >= 0.f) ? msg : NEG_SLOPE * msg;
    float ex = expf(lr * att[0] - ((const float*)sc)[3]);
    atomicAdd(&NS[d].x, ex);
    atomicAdd(&NS[d].y, ex * sa.y);
}

__global__ void k_logits(const float2* __restrict__ NS, const float* __restrict__ bias,
                         float* __restrict__ logits, unsigned* sc, int n) {
    int i = blockIdx.x * blockDim.x + threadIdx.x;
    unsigned mu = 0u;
    if (i < n) {
        float2 ns = NS[i];
        float lg = ns.y / (ns.x + 1e-38f) + bias[0];
        logits[i] = lg;
        mu = fmap(lg);
    }
    #pragma unroll
    for (int o = 32; o; o >>= 1) { unsigned t = __shfl_xor(mu, o); mu = (t > mu) ? t : mu; }
    if ((threadIdx.x & 63) == 0) atomicMax(&sc[0], mu);
}

__global__ void k_pool2(const float4* __restrict__ partial, int nblk1, unsigned* pooled_u) {
    int sub = threadIdx.x >> 6;
    int lane = threadIdx.x & 63;
    int chunk = (nblk1 + gridDim.x - 1) / gridDim.x;
    int b0 = blockIdx.x * chunk;
    int b1 = min(b0 + chunk, nblk1);
    float4 m = make_float4(-INFINITY, -INFINITY, -INFINITY, -INFINITY);
    for (int b = b0 + sub; b < b1; b += 4) {
        float4 v = partial[(size_t)b * 64 + lane];
        m.x = fmaxf(m.x, v.x); m.y = fmaxf(m.y, v.y);
        m.z = fmaxf(m.z, v.z); m.w = fmaxf(m.w, v.w);
    }
    __shared__ float4 red[256];
    red[threadIdx.x] = m;
    __syncthreads();
    if (sub == 0) {
        float4 a = red[lane], b = red[64 + lane], c = red[128 + lane], d = red[192 + lane];
        a.x = fmaxf(fmaxf(a.x, b.x), fmaxf(c.x, d.x));
        a.y = fmaxf(fmaxf(a.y, b.y), fmaxf(c.y, d.y));
        a.z = fmaxf(fmaxf(a.z, b.z), fmaxf(c.z, d.z));
        a.w = fmaxf(fmaxf(a.w, b.w), fmaxf(c.w, d.w));
        atomicMax(&pooled_u[lane * 4 + 0], fmap(a.x));
        atomicMax(&pooled_u[lane * 4 + 1], fmap(a.y));
        atomicMax(&pooled_u[lane * 4 + 2], fmap(a.z));
        atomicMax(&pooled_u[lane * 4 + 3], fmap(a.w));
    }
}

__global__ void k_poolwrite(const unsigned* __restrict__ pooled_u, float* __restrict__ out, int n) {
    int t = threadIdx.x;
    out[n + t] = funmap(pooled_u[t]);
}

extern "C" void kernel_launch(void* const* d_in, const int* in_sizes, int n_in,
                              void* d_out, int out_size, void* d_ws, size_t ws_size,
                              hipStream_t stream) {
    const float* x    = (const float*)d_in[0];
    const float* pos  = (const float*)d_in[1];
    const float* w_l  = (const float*)d_in[2];
    const float* w_r  = (const float*)d_in[3];
    const float* w_e  = (const float*)d_in[4];
    const float* att  = (const float*)d_in[5];
    const float* bias = (const float*)d_in[6];
    const int*   ei   = (const int*)d_in[7];

    const int n = in_sizes[0] / D_FEAT;     // 100000
    const int E = in_sizes[7] / 2;          // 3200000
    const int* src = ei;
    const int* dst = ei + E;
    const int nbins = (n + 255) >> 8;       // 391
    const int nW = (n + 3) / 4;             // stamp words
    const int nBlkScat = (E + 8191) / 8192; // 391
    const int Bk = 256;
    const int gN  = (n + Bk - 1) / Bk;
    const int gE  = (E + Bk - 1) / Bk;
    const int gD  = (n + 3) / 4;            // fallback k_dots blocks
    const int gP  = (n + 15) / 16;          // k_pre blocks (16 nodes/block)
    const int E4  = E / 4;
    const int gE4 = (E4 + Bk - 1) / Bk;
    const int POOLB = 2048;                 // pool1 grid
    const int POOL2B = 16;                  // pool2g grid

    float* f0 = (float*)d_ws;
    size_t o = 0;
    float*    xl       = f0 + o; o += (size_t)n;                  // fallback only
    float*    xr       = f0 + o; o += (size_t)n;                  // fallback only
    float2*   sA       = (float2*)(f0 + o); o += 2 * (size_t)n;
    float*    B        = f0 + o; o += (size_t)n;
    float*    logits   = f0 + o; o += (size_t)n;
    o = (o + 3) & ~(size_t)3;
    float2*   NS       = (float2*)(f0 + o); o += 2 * (size_t)n;   // fallback NS / fallback partials
    float4*   partialF = (float4*)NS;
    unsigned* stampW   = (unsigned*)(f0 + o); o += (size_t)nW;
    unsigned char* stamp = (unsigned char*)stampW;
    unsigned* pooled_u = (unsigned*)(f0 + o); o += 256;
    unsigned* sc       = (unsigned*)(f0 + o); o += 64;
    unsigned* gBase    = (unsigned*)(f0 + o); o += MAXBINS;
    unsigned* gCursor  = (unsigned*)(f0 + o); o += MAXBINS;
    unsigned* gHist    = (unsigned*)(f0 + o); o += MAXBINS;
    o = (o + 3) & ~(size_t)3;
    float4*   gABpart  = (float4*)(f0 + o); o += 4 * (size_t)gP;
    o = (o + 15) & ~(size_t)15;                                   // 64B align
    unsigned* recs     = (unsigned*)(f0 + o);
    float4*   partialT = (float4*)recs;                            // reuse recs after BFS
    float4*   partial2 = (float4*)(recs + (size_t)POOLB * 256);    // after partialT

    size_t capWords = (size_t)E + (size_t)nbins * (15u * (size_t)nBlkScat + 16u);
    size_t poolWords = (size_t)POOLB * 256 + (size_t)POOL2B * 256;
    if (poolWords > capWords) capWords = poolWords;
    size_t need_bytes = (o + capWords) * sizeof(float);
    const bool sorted_ok = (ws_size >= need_bytes) && (nbins <= MAXBINS) &&
                           (E % 4 == 0) && (n <= (1 << 17));

    float* out = (float*)d_out;

    if (sorted_ok) {
        k_pre<<<gP, Bk, 0, stream>>>(x, w_l, w_r, pos, w_e, sA, B, gABpart,
                                     stampW, gHist, sc, n, nW);
        k_hist<<<512, Bk, 0, stream>>>((const int4*)dst, E4, nbins, gHist,
                                       gABpart, gP, gBase, gCursor,
                                       nBlkScat, sc, att);
        k_scatter<<<nBlkScat, 512, 0, stream>>>((const int4*)src, (const int4*)dst,
                                                gCursor, recs, E4, nbins);
        k_binsum<<<nbins, Bk, 0, stream>>>((const uint4*)recs, gBase, gCursor, sA, B,
                                           att, bias, logits, sc, n);
        k_sumarg<<<gN, Bk, 0, stream>>>(logits, sc, n);
        k_score<<<gN, Bk, 0, stream>>>(logits, sc, out, stamp, n);
        for (int t = 1; t <= 4; ++t) {
            k_bfs_stamp<<<gE4, Bk, 0, stream>>>((const int4*)src, (const int4*)dst,
                                                stamp, E4, t);
        }
        k_bfs_rec<<<nbins, Bk, 0, stream>>>((const uint4*)recs, gBase, gCursor,
                                            stamp, n, 5);
        k_pool1<<<POOLB, Bk, 0, stream>>>(x, stamp, partialT, n);
        k_pool2g<<<POOL2B, Bk, 0, stream>>>(partialT, POOLB, partial2, sc, out, n);
    } else {
        k_init<<<gN, Bk, 0, stream>>>(NS, stampW, nW, pooled_u, sc, n);
        k_dots<<<gD, Bk, 0, stream>>>(x, w_l, w_r, xl, xr, n);
        k_ab<<<gN, Bk, 0, stream>>>(xl, xr, pos, w_e, sA, B, sc, n);
        k_scanM<<<1, 64, 0, stream>>>(sc, att);
        k_edge_sum<<<gE, Bk, 0, stream>>>(src, dst, sA, B, att, sc, NS, E);
        k_logits<<<gN, Bk, 0, stream>>>(NS, bias, logits, sc, n);
        k_sumarg<<<gN, Bk, 0, stream>>>(logits, sc, n);
        k_score<<<gN, Bk, 0, stream>>>(logits, sc, out, stamp, n);
        for (int t = 1; t <= 5; ++t) {
            k_bfs_stamp<<<gE4, Bk, 0, stream>>>((const int4*)src, (const int4*)dst,
                                                stamp, E4, t);
        }
        int nblk1 = (int)((2 * (size_t)n) / 256);
        if (nblk1 > 768) nblk1 = 768;
        if (nblk1 < 1) nblk1 = 1;
        k_pool1<<<nblk1, Bk, 0, stream>>>(x, stamp, partialF, n);
        k_pool2<<<16, Bk, 0, stream>>>(partialF, nblk1, pooled_u);
        k_poolwrite<<<1, Bk, 0, stream>>>(pooled_u, out, n);
    }
}

// Round 13
// 264.302 us; speedup vs baseline: 1.0519x; 1.0519x over previous
//
#include <hip/hip_runtime.h>

#define D_FEAT 256
#define NEG_SLOPE 0.2f
#define MAXBINS 512
#define SENT 0xFFFFFFFFu

__device__ __forceinline__ unsigned fmap(float f) {
    unsigned u = __float_as_uint(f);
    return (u & 0x80000000u) ? ~u : (u | 0x80000000u);
}
__device__ __forceinline__ float funmap(unsigned u) {
    return __uint_as_float((u & 0x80000000u) ? (u ^ 0x80000000u) : ~u);
}
__device__ __forceinline__ float dot4(float4 v, float4 w) {
    return v.x * w.x + v.y * w.y + v.z * w.z + v.w * w.w;
}

// sc layout: [0] gmax_u  [1] gsum(f32)  [2] argmin  [3] M(f32)
//            [4..7] fallback AB extrema  [8] pool done-counter

// ---------------- sorted-path preamble: dots+ab, 4 nodes/wave ----------------
__global__ void k_pre(const float* __restrict__ x, const float* __restrict__ w_l,
                      const float* __restrict__ w_r, const float* __restrict__ pos,
                      const float* __restrict__ w_e,
                      float2* __restrict__ sA, float* __restrict__ Bv,
                      float4* __restrict__ gABpart, unsigned* __restrict__ stampW,
                      unsigned* __restrict__ gHist, unsigned* __restrict__ sc,
                      int n, int nW) {
    int blk = blockIdx.x, tid = threadIdx.x;
    int gid = blk * 256 + tid;
    if (gid < nW) stampW[gid] = 0xFFFFFFFFu;
    if (blk == 0) {
        if (tid < MAXBINS) gHist[tid] = 0u;
        if (tid + 256 < MAXBINS) gHist[tid + 256] = 0u;
        if (tid == 0) sc[8] = 0u;
    }
    int w = tid >> 6, lane = tid & 63;
    int node0 = blk * 16 + w * 4;
    float4 al = ((const float4*)w_l)[lane];
    float4 bl = ((const float4*)w_r)[lane];
    float sl0 = 0.f, sl1 = 0.f, sl2 = 0.f, sl3 = 0.f;
    float sr0 = 0.f, sr1 = 0.f, sr2 = 0.f, sr3 = 0.f;
    if (node0 + 3 < n) {
        float4 v0 = ((const float4*)(x + (size_t)node0 * D_FEAT))[lane];
        float4 v1 = ((const float4*)(x + (size_t)(node0 + 1) * D_FEAT))[lane];
        float4 v2 = ((const float4*)(x + (size_t)(node0 + 2) * D_FEAT))[lane];
        float4 v3 = ((const float4*)(x + (size_t)(node0 + 3) * D_FEAT))[lane];
        sl0 = dot4(v0, al); sr0 = dot4(v0, bl);
        sl1 = dot4(v1, al); sr1 = dot4(v1, bl);
        sl2 = dot4(v2, al); sr2 = dot4(v2, bl);
        sl3 = dot4(v3, al); sr3 = dot4(v3, bl);
    } else if (node0 < n) {
        {
            float4 v = ((const float4*)(x + (size_t)node0 * D_FEAT))[lane];
            sl0 = dot4(v, al); sr0 = dot4(v, bl);
        }
        if (node0 + 1 < n) {
            float4 v = ((const float4*)(x + (size_t)(node0 + 1) * D_FEAT))[lane];
            sl1 = dot4(v, al); sr1 = dot4(v, bl);
        }
        if (node0 + 2 < n) {
            float4 v = ((const float4*)(x + (size_t)(node0 + 2) * D_FEAT))[lane];
            sl2 = dot4(v, al); sr2 = dot4(v, bl);
        }
    }
    #pragma unroll
    for (int o = 32; o; o >>= 1) {
        sl0 += __shfl_xor(sl0, o); sr0 += __shfl_xor(sr0, o);
        sl1 += __shfl_xor(sl1, o); sr1 += __shfl_xor(sr1, o);
        sl2 += __shfl_xor(sl2, o); sr2 += __shfl_xor(sr2, o);
        sl3 += __shfl_xor(sl3, o); sr3 += __shfl_xor(sr3, o);
    }
    float amax = -INFINITY, bmaxv = -INFINITY, amin = INFINITY, bminv = INFINITY;
    int node = node0 + lane;
    if (lane < 4 && node < n) {
        float slv = (lane == 0) ? sl0 : (lane == 1) ? sl1 : (lane == 2) ? sl2 : sl3;
        float srv = (lane == 0) ? sr0 : (lane == 1) ? sr1 : (lane == 2) ? sr2 : sr3;
        float p = pos[3 * node] * w_e[0] + pos[3 * node + 1] * w_e[1]
                + pos[3 * node + 2] * w_e[2];
        float a = slv - p, b = srv + p;
        sA[node] = make_float2(a, slv);
        Bv[node] = b;
        amax = a; amin = a; bmaxv = b; bminv = b;
    }
    #pragma unroll
    for (int o = 1; o < 4; o <<= 1) {
        amax = fmaxf(amax, __shfl_xor(amax, o));
        bmaxv = fmaxf(bmaxv, __shfl_xor(bmaxv, o));
        amin = fminf(amin, __shfl_xor(amin, o));
        bminv = fminf(bminv, __shfl_xor(bminv, o));
    }
    __shared__ float s4[4][4];
    if (lane == 0) { s4[w][0] = amax; s4[w][1] = bmaxv; s4[w][2] = amin; s4[w][3] = bminv; }
    __syncthreads();
    if (tid == 0) {
        float AM = s4[0][0], BM = s4[0][1], Am = s4[0][2], Bm = s4[0][3];
        #pragma unroll
        for (int k = 1; k < 4; ++k) {
            AM = fmaxf(AM, s4[k][0]); BM = fmaxf(BM, s4[k][1]);
            Am = fminf(Am, s4[k][2]); Bm = fminf(Bm, s4[k][3]);
        }
        gABpart[blk] = make_float4(AM, BM, Am, Bm);
    }
}

// 512 blocks grid-stride: dst-bin histogram
__global__ void k_hist(const int4* __restrict__ dst4, int E4, int nbins,
                       unsigned* __restrict__ gHist) {
    __shared__ unsigned h[MAXBINS];
    for (int b = threadIdx.x; b < nbins; b += blockDim.x) h[b] = 0u;
    __syncthreads();
    int stride = gridDim.x * blockDim.x;
    for (int i = blockIdx.x * blockDim.x + threadIdx.x; i < E4; i += stride) {
        int4 d = dst4[i];
        atomicAdd(&h[d.x >> 8], 1u);
        atomicAdd(&h[d.y >> 8], 1u);
        atomicAdd(&h[d.z >> 8], 1u);
        atomicAdd(&h[d.w >> 8], 1u);
    }
    __syncthreads();
    for (int b = threadIdx.x; b < nbins; b += blockDim.x)
        if (h[b]) atomicAdd(&gHist[b], h[b]);
}

// One block: reduce gABpart -> M; init sc[0..2]; scan padded capacities.
__global__ void k_scan2(const float4* __restrict__ gABpart, int nAB,
                        const unsigned* __restrict__ gHist,
                        unsigned* __restrict__ gBase, unsigned* __restrict__ gCursor,
                        int nbins, int nBlk, unsigned* sc, const float* __restrict__ att) {
    int tid = threadIdx.x;
    float AM = -INFINITY, BM = -INFINITY, Am = INFINITY, Bm = INFINITY;
    for (int i = tid; i < nAB; i += 256) {
        float4 v = gABpart[i];
        AM = fmaxf(AM, v.x); BM = fmaxf(BM, v.y);
        Am = fminf(Am, v.z); Bm = fminf(Bm, v.w);
    }
    #pragma unroll
    for (int o = 32; o; o >>= 1) {
        AM = fmaxf(AM, __shfl_xor(AM, o)); BM = fmaxf(BM, __shfl_xor(BM, o));
        Am = fminf(Am, __shfl_xor(Am, o)); Bm = fminf(Bm, __shfl_xor(Bm, o));
    }
    __shared__ float s4[4][4];
    int w = tid >> 6, lane = tid & 63;
    if (lane == 0) { s4[w][0] = AM; s4[w][1] = BM; s4[w][2] = Am; s4[w][3] = Bm; }
    __syncthreads();
    if (tid == 0) {
        float am = s4[0][0], bm = s4[0][1], an = s4[0][2], bn = s4[0][3];
        #pragma unroll
        for (int k = 1; k < 4; ++k) {
            am = fmaxf(am, s4[k][0]); bm = fmaxf(bm, s4[k][1]);
            an = fminf(an, s4[k][2]); bn = fminf(bn, s4[k][3]);
        }
        float at = att[0];
        float z = (at >= 0.f) ? (am + bm) : (an + bn);
        float lz = (z >= 0.f) ? z : NEG_SLOPE * z;
        ((float*)sc)[3] = lz * at;
        sc[0] = 0u; ((float*)sc)[1] = 0.f; sc[2] = 0xFFFFFFFFu;
    }
    __syncthreads();
    if (tid < 64) {
        unsigned padw = 15u * (unsigned)nBlk;
        unsigned carry = 0;
        for (int b0 = 0; b0 < nbins; b0 += 64) {
            int b = b0 + tid;
            unsigned v = (b < nbins) ? ((gHist[b] + padw + 15u) & ~15u) : 0u;
            unsigned inc = v;
            #pragma unroll
            for (int o = 1; o < 64; o <<= 1) {
                unsigned t = __shfl_up(inc, o);
                if (tid >= o) inc += t;
            }
            unsigned excl = inc - v + carry;
            if (b < nbins) { gBase[b] = excl; gCursor[b] = excl; }
            carry += __shfl(inc, 63);
        }
    }
}

// 512 threads, 8192 edges/block. LDS hist -> 16-word-aligned runs ->
// scatter 4B words  src | (dst&255)<<17; pad runs with SENT.
__global__ void k_scatter(const int4* __restrict__ src4, const int4* __restrict__ dst4,
                          unsigned* __restrict__ gCursor, unsigned* __restrict__ recs,
                          int E4, int nbins) {
    __shared__ unsigned h[MAXBINS];
    __shared__ unsigned base[MAXBINS];
    for (int b = threadIdx.x; b < nbins; b += 512) h[b] = 0u;
    __syncthreads();
    int b4 = blockIdx.x * 2048;
    #pragma unroll
    for (int g = 0; g < 4; ++g) {
        int idx = b4 + g * 512 + threadIdx.x;
        if (idx < E4) {
            int4 d = dst4[idx];
            atomicAdd(&h[d.x >> 8], 1u);
            atomicAdd(&h[d.y >> 8], 1u);
            atomicAdd(&h[d.z >> 8], 1u);
            atomicAdd(&h[d.w >> 8], 1u);
        }
    }
    __syncthreads();
    for (int b = threadIdx.x; b < nbins; b += 512) {
        unsigned c = h[b];
        h[b] = 0u;
        base[b] = c ? atomicAdd(&gCursor[b], (c + 15u) & ~15u) : 0u;
    }
    __syncthreads();
    #pragma unroll
    for (int g = 0; g < 4; ++g) {
        int idx = b4 + g * 512 + threadIdx.x;
        if (idx < E4) {
            int4 sv = src4[idx];
            int4 dv = dst4[idx];
            int ss[4] = { sv.x, sv.y, sv.z, sv.w };
            int dd[4] = { dv.x, dv.y, dv.z, dv.w };
            #pragma unroll
            for (int j = 0; j < 4; ++j) {
                int d_ = dd[j];
                int bin = d_ >> 8;
                unsigned off = atomicAdd(&h[bin], 1u);
                recs[base[bin] + off] = (unsigned)ss[j] | ((unsigned)(d_ & 255) << 17);
            }
        }
    }
    __syncthreads();
    for (int b = threadIdx.x; b < nbins; b += 512) {
        unsigned c = h[b];
        unsigned pc = (c + 15u) & ~15u;
        for (unsigned k = c; k < pc; ++k) recs[base[b] + k] = SENT;
    }
}

// One block per bin: uint4 record loads, recompute ex, LDS accumulate,
// fused logits + global max.
__global__ void k_binsum(const uint4* __restrict__ recs4, const unsigned* __restrict__ gBase,
                         const unsigned* __restrict__ gCursor,
                         const float2* __restrict__ sA, const float* __restrict__ Bv,
                         const float* __restrict__ att, const float* __restrict__ bias,
                         float* __restrict__ logits, unsigned* sc, int n) {
    __shared__ float accx[256];
    __shared__ float accy[256];
    __shared__ float Bb[256];
    int b = blockIdx.x;
    int tid = threadIdx.x;
    int node0 = b << 8;
    accx[tid] = 0.f; accy[tid] = 0.f;
    Bb[tid] = (node0 + tid < n) ? Bv[node0 + tid] : 0.f;
    __syncthreads();
    const float at = att[0];
    const float M = ((const float*)sc)[3];
    unsigned q0 = gBase[b] >> 2, q1 = gCursor[b] >> 2;
    for (unsigned i = q0 + tid; i < q1; i += 256u) {
        uint4 r4 = recs4[i];
        unsigned ws[4] = { r4.x, r4.y, r4.z, r4.w };
        #pragma unroll
        for (int j = 0; j < 4; ++j) {
            unsigned wv = ws[j];
            if (wv == SENT) continue;
            int sidx = (int)(wv & 0x1FFFFu);
            int loc  = (int)(wv >> 17);
            float2 sa = sA[sidx];
            float msg = sa.x + Bb[loc];
            float lr = (msg >= 0.f) ? msg : NEG_SLOPE * msg;
            float e = expf(lr * at - M);
            atomicAdd(&accx[loc], e);
            atomicAdd(&accy[loc], e * sa.y);
        }
    }
    __syncthreads();
    int node = node0 + tid;
    float lg = -INFINITY;
    if (node < n) {
        lg = accy[tid] / (accx[tid] + 1e-38f) + bias[0];
        logits[node] = lg;
    }
    unsigned mu = fmap(lg);
    #pragma unroll
    for (int o = 32; o; o >>= 1) { unsigned t = __shfl_xor(mu, o); mu = (t > mu) ? t : mu; }
    __shared__ unsigned wm[4];
    int w_ = tid >> 6, l = tid & 63;
    if (l == 0) wm[w_] = mu;
    __syncthreads();
    if (tid == 0) {
        unsigned m = wm[0];
        #pragma unroll
        for (int k = 1; k < 4; ++k) m = (wm[k] > m) ? wm[k] : m;
        atomicMax(&sc[0], m);
    }
}

// ---------------- tail kernels ----------------

// sum of exp(l-gmax) + first argmax; stores ex back into logits (logits dead after)
__global__ void k_sumarg(float* __restrict__ logits, unsigned* sc, int n) {
    int i = blockIdx.x * blockDim.x + threadIdx.x;
    unsigned gmax_u = sc[0];
    float gmax = funmap(gmax_u);
    float ex = 0.f;
    if (i < n) {
        float lg = logits[i];
        ex = expf(lg - gmax);
        if (fmap(lg) == gmax_u) atomicMin(&sc[2], (unsigned)i);
        logits[i] = ex;
    }
    #pragma unroll
    for (int o = 32; o; o >>= 1) ex += __shfl_xor(ex, o);
    if ((threadIdx.x & 63) == 0) atomicAdd((float*)&sc[1], ex);
}

// out = stored_ex / gsum ; seed BFS stamp at argmax
__global__ void k_score(const float* __restrict__ logits, const unsigned* __restrict__ sc,
                        float* __restrict__ out, unsigned char* stamp, int n) {
    int i = blockIdx.x * blockDim.x + threadIdx.x;
    if (i >= n) return;
    float gsum = ((const float*)sc)[1];
    out[i] = logits[i] / gsum;
    if (i == (int)sc[2]) stamp[i] = 0;
}

// In-place timestamp BFS pass t.
__global__ void k_bfs_stamp(const int4* __restrict__ src4, const int4* __restrict__ dst4,
                            unsigned char* __restrict__ stamp, int E4, int t) {
    int i = blockIdx.x * blockDim.x + threadIdx.x;
    if (i >= E4) return;
    int4 s = src4[i];
    unsigned char th = (unsigned char)t;
    bool h0 = stamp[s.x] < th;
    bool h1 = stamp[s.y] < th;
    bool h2 = stamp[s.z] < th;
    bool h3 = stamp[s.w] < th;
    if (!(h0 | h1 | h2 | h3)) return;
    int4 d = dst4[i];
    if (h0 && stamp[d.x] > th) stamp[d.x] = th;
    if (h1 && stamp[d.y] > th) stamp[d.y] = th;
    if (h2 && stamp[d.z] > th) stamp[d.z] = th;
    if (h3 && stamp[d.w] > th) stamp[d.w] = th;
}

// pool stage 1: conditional float4 loads, wave-uniform stamp skip
__global__ void k_pool1(const float* __restrict__ x, const unsigned char* __restrict__ stamp,
                        float4* __restrict__ partial, int n) {
    int sub = threadIdx.x >> 6;
    int lane = threadIdx.x & 63;
    float4 m = make_float4(-INFINITY, -INFINITY, -INFINITY, -INFINITY);
    int stride = gridDim.x * 4;
    for (int node = blockIdx.x * 4 + sub; node < n; node += stride) {
        if (stamp[node] != 0xFF) {
            float4 v = ((const float4*)(x + (size_t)node * D_FEAT))[lane];
            m.x = fmaxf(m.x, v.x); m.y = fmaxf(m.y, v.y);
            m.z = fmaxf(m.z, v.z); m.w = fmaxf(m.w, v.w);
        }
    }
    __shared__ float4 red[256];
    red[threadIdx.x] = m;
    __syncthreads();
    if (sub == 0) {
        float4 a = red[lane], b = red[64 + lane], c = red[128 + lane], d = red[192 + lane];
        a.x = fmaxf(fmaxf(a.x, b.x), fmaxf(c.x, d.x));
        a.y = fmaxf(fmaxf(a.y, b.y), fmaxf(c.y, d.y));
        a.z = fmaxf(fmaxf(a.z, b.z), fmaxf(c.z, d.z));
        a.w = fmaxf(fmaxf(a.w, b.w), fmaxf(c.w, d.w));
        partial[(size_t)blockIdx.x * 64 + lane] = a;
    }
}

// pool stage 2: 16 blocks reduce partial rows -> partial2; last block
// (done-counter sc[8]) reduces 16 rows straight into out[n..n+255].
__global__ void k_pool2g(const float4* __restrict__ partial, int nblk1,
                         float4* __restrict__ partial2, unsigned* sc,
                         float* __restrict__ out, int n) {
    int sub = threadIdx.x >> 6;
    int lane = threadIdx.x & 63;
    int chunk = (nblk1 + gridDim.x - 1) / gridDim.x;
    int b0 = blockIdx.x * chunk;
    int b1 = min(b0 + chunk, nblk1);
    float4 m = make_float4(-INFINITY, -INFINITY, -INFINITY, -INFINITY);
    for (int b = b0 + sub; b < b1; b += 4) {
        float4 v = partial[(size_t)b * 64 + lane];
        m.x = fmaxf(m.x, v.x); m.y = fmaxf(m.y, v.y);
        m.z = fmaxf(m.z, v.z); m.w = fmaxf(m.w, v.w);
    }
    __shared__ float4 red[256];
    red[threadIdx.x] = m;
    __syncthreads();
    if (sub == 0) {
        float4 a = red[lane], b = red[64 + lane], c = red[128 + lane], d = red[192 + lane];
        a.x = fmaxf(fmaxf(a.x, b.x), fmaxf(c.x, d.x));
        a.y = fmaxf(fmaxf(a.y, b.y), fmaxf(c.y, d.y));
        a.z = fmaxf(fmaxf(a.z, b.z), fmaxf(c.z, d.z));
        a.w = fmaxf(fmaxf(a.w, b.w), fmaxf(c.w, d.w));
        partial2[(size_t)blockIdx.x * 64 + lane] = a;
    }
    __threadfence();
    __shared__ unsigned done;
    if (threadIdx.x == 0) done = atomicAdd(&sc[8], 1u);
    __syncthreads();
    if (done != (unsigned)(gridDim.x - 1)) return;
    __threadfence();
    float4 m2 = make_float4(-INFINITY, -INFINITY, -INFINITY, -INFINITY);
    for (int r = sub; r < (int)gridDim.x; r += 4) {
        float4 v = partial2[(size_t)r * 64 + lane];
        m2.x = fmaxf(m2.x, v.x); m2.y = fmaxf(m2.y, v.y);
        m2.z = fmaxf(m2.z, v.z); m2.w = fmaxf(m2.w, v.w);
    }
    __syncthreads();
    red[threadIdx.x] = m2;
    __syncthreads();
    if (sub == 0) {
        float4 a = red[lane], b = red[64 + lane], c = red[128 + lane], d = red[192 + lane];
        a.x = fmaxf(fmaxf(a.x, b.x), fmaxf(c.x, d.x));
        a.y = fmaxf(fmaxf(a.y, b.y), fmaxf(c.y, d.y));
        a.z = fmaxf(fmaxf(a.z, b.z), fmaxf(c.z, d.z));
        a.w = fmaxf(fmaxf(a.w, b.w), fmaxf(c.w, d.w));
        out[n + 4 * lane + 0] = a.x;
        out[n + 4 * lane + 1] = a.y;
        out[n + 4 * lane + 2] = a.z;
        out[n + 4 * lane + 3] = a.w;
    }
}

// ---------------- fallback (atomic) path kernels ----------------

__global__ void k_init(float2* NS, unsigned* stampW, int nW, unsigned* pooled_u,
                       unsigned* sc, int n) {
    int i = blockIdx.x * blockDim.x + threadIdx.x;
    if (i < n) NS[i] = make_float2(0.f, 0.f);
    if (i < nW) stampW[i] = 0xFFFFFFFFu;
    if (i < D_FEAT) pooled_u[i] = 0u;
    if (i == 0) {
        sc[0] = 0u; ((float*)sc)[1] = 0.f; sc[2] = 0xFFFFFFFFu;
        sc[4] = 0u; sc[5] = 0u; sc[6] = 0xFFFFFFFFu; sc[7] = 0xFFFFFFFFu;
    }
}

__global__ void k_dots(const float* __restrict__ x, const float* __restrict__ w_l,
                       const float* __restrict__ w_r, float* __restrict__ xl,
                       float* __restrict__ xr, int n) {
    int wave = (int)((blockIdx.x * blockDim.x + threadIdx.x) >> 6);
    int lane = threadIdx.x & 63;
    if (wave >= n) return;
    const float4* xv = (const float4*)(x + (size_t)wave * D_FEAT);
    float4 v = xv[lane];
    float4 a = ((const float4*)w_l)[lane];
    float4 b = ((const float4*)w_r)[lane];
    float sl = dot4(v, a);
    float sr = dot4(v, b);
    #pragma unroll
    for (int o = 32; o; o >>= 1) { sl += __shfl_xor(sl, o); sr += __shfl_xor(sr, o); }
    if (lane == 0) { xl[wave] = sl; xr[wave] = sr; }
}

__global__ void k_ab(const float* __restrict__ xl, const float* __restrict__ xr,
                     const float* __restrict__ pos, const float* __restrict__ w_e,
                     float2* __restrict__ sA, float* __restrict__ B,
                     unsigned* sc, int n) {
    int i = blockIdx.x * blockDim.x + threadIdx.x;
    float amax, amin, bmax, bmin;
    if (i < n) {
        float p = pos[3 * i] * w_e[0] + pos[3 * i + 1] * w_e[1] + pos[3 * i + 2] * w_e[2];
        float xli = xl[i];
        float a = xli - p;
        float b = xr[i] + p;
        sA[i] = make_float2(a, xli);
        B[i] = b;
        amax = amin = a; bmax = bmin = b;
    } else {
        amax = bmax = -INFINITY; amin = bmin = INFINITY;
    }
    #pragma unroll
    for (int o = 32; o; o >>= 1) {
        amax = fmaxf(amax, __shfl_xor(amax, o));
        bmax = fmaxf(bmax, __shfl_xor(bmax, o));
        amin = fminf(amin, __shfl_xor(amin, o));
        bmin = fminf(bmin, __shfl_xor(bmin, o));
    }
    __shared__ float s4[4][4];
    int w = threadIdx.x >> 6, l = threadIdx.x & 63;
    if (l == 0) { s4[w][0] = amax; s4[w][1] = bmax; s4[w][2] = amin; s4[w][3] = bmin; }
    __syncthreads();
    if (threadIdx.x == 0) {
        float AM = s4[0][0], BM = s4[0][1], Am = s4[0][2], Bm = s4[0][3];
        #pragma unroll
        for (int k = 1; k < 4; ++k) {
            AM = fmaxf(AM, s4[k][0]); BM = fmaxf(BM, s4[k][1]);
            Am = fminf(Am, s4[k][2]); Bm = fminf(Bm, s4[k][3]);
        }
        atomicMax(&sc[4], fmap(AM)); atomicMax(&sc[5], fmap(BM));
        atomicMin(&sc[6], fmap(Am)); atomicMin(&sc[7], fmap(Bm));
    }
}

__global__ void k_scanM(unsigned* sc, const float* __restrict__ att) {
    if (threadIdx.x == 0) {
        float at = att[0];
        float z = (at >= 0.f) ? (funmap(sc[4]) + funmap(sc[5]))
                              : (funmap(sc[6]) + funmap(sc[7]));
        float lz = (z >= 0.f) ? z : NEG_SLOPE * z;
        ((float*)sc)[3] = lz * at;
        sc[0] = 0u; ((float*)sc)[1] = 0.f; sc[2] = 0xFFFFFFFFu;
    }
}

__global__ void k_edge_sum(const int* __restrict__ src, const int* __restrict__ dst,
                           const float2* __restrict__ sA, const float* __restrict__ B,
                           const float* __restrict__ att, const unsigned* __restrict__ sc,
                           float2* NS, int E) {
    int i = blockIdx.x * blockDim.x + threadIdx.x;
    if (i >= E) return;
    int s = src[i], d = dst[i];
    float2 sa = sA[s];
    float msg = sa.x + B[d];
    float lr = (msg >= 0.f) ? msg : NEG_SLOPE * msg;
    float ex = expf(lr * att[0] - ((const float*)sc)[3]);
    atomicAdd(&NS[d].x, ex);
    atomicAdd(&NS[d].y, ex * sa.y);
}

__global__ void k_logits(const float2* __restrict__ NS, const float* __restrict__ bias,
                         float* __restrict__ logits, unsigned* sc, int n) {
    int i = blockIdx.x * blockDim.x + threadIdx.x;
    unsigned mu = 0u;
    if (i < n) {
        float2 ns = NS[i];
        float lg = ns.y / (ns.x + 1e-38f) + bias[0];
        logits[i] = lg;
        mu = fmap(lg);
    }
    #pragma unroll
    for (int o = 32; o; o >>= 1) { unsigned t = __shfl_xor(mu, o); mu = (t > mu) ? t : mu; }
    if ((threadIdx.x & 63) == 0) atomicMax(&sc[0], mu);
}

__global__ void k_pool2(const float4* __restrict__ partial, int nblk1, unsigned* pooled_u) {
    int sub = threadIdx.x >> 6;
    int lane = threadIdx.x & 63;
    int chunk = (nblk1 + gridDim.x - 1) / gridDim.x;
    int b0 = blockIdx.x * chunk;
    int b1 = min(b0 + chunk, nblk1);
    float4 m = make_float4(-INFINITY, -INFINITY, -INFINITY, -INFINITY);
    for (int b = b0 + sub; b < b1; b += 4) {
        float4 v = partial[(size_t)b * 64 + lane];
        m.x = fmaxf(m.x, v.x); m.y = fmaxf(m.y, v.y);
        m.z = fmaxf(m.z, v.z); m.w = fmaxf(m.w, v.w);
    }
    __shared__ float4 red[256];
    red[threadIdx.x] = m;
    __syncthreads();
    if (sub == 0) {
        float4 a = red[lane], b = red[64 + lane], c = red[128 + lane], d = red[192 + lane];
        a.x = fmaxf(fmaxf(a.x, b.x), fmaxf(c.x, d.x));
        a.y = fmaxf(fmaxf(a.y, b.y), fmaxf(c.y, d.y));
        a.z = fmaxf(fmaxf(a.z, b.z), fmaxf(c.z, d.z));
        a.w = fmaxf(fmaxf(a.w, b.w), fmaxf(c.w, d.w));
        atomicMax(&pooled_u[lane * 4 + 0], fmap(a.x));
        atomicMax(&pooled_u[lane * 4 + 1], fmap(a.y));
        atomicMax(&pooled_u[lane * 4 + 2], fmap(a.z));
        atomicMax(&pooled_u[lane * 4 + 3], fmap(a.w));
    }
}

__global__ void k_poolwrite(const unsigned* __restrict__ pooled_u, float* __restrict__ out, int n) {
    int t = threadIdx.x;
    out[n + t] = funmap(pooled_u[t]);
}

extern "C" void kernel_launch(void* const* d_in, const int* in_sizes, int n_in,
                              void* d_out, int out_size, void* d_ws, size_t ws_size,
                              hipStream_t stream) {
    const float* x    = (const float*)d_in[0];
    const float* pos  = (const float*)d_in[1];
    const float* w_l  = (const float*)d_in[2];
    const float* w_r  = (const float*)d_in[3];
    const float* w_e  = (const float*)d_in[4];
    const float* att  = (const float*)d_in[5];
    const float* bias = (const float*)d_in[6];
    const int*   ei   = (const int*)d_in[7];

    const int n = in_sizes[0] / D_FEAT;     // 100000
    const int E = in_sizes[7] / 2;          // 3200000
    const int* src = ei;
    const int* dst = ei + E;
    const int nbins = (n + 255) >> 8;       // 391
    const int nW = (n + 3) / 4;             // stamp words
    const int nBlkScat = (E + 8191) / 8192; // 391
    const int Bk = 256;
    const int gN  = (n + Bk - 1) / Bk;
    const int gE  = (E + Bk - 1) / Bk;
    const int gD  = (n + 3) / 4;            // fallback k_dots blocks
    const int gP  = (n + 15) / 16;          // k_pre blocks (16 nodes/block)
    const int E4  = E / 4;
    const int gE4 = (E4 + Bk - 1) / Bk;
    const int POOLB = 2048;                 // pool1 grid
    const int POOL2B = 16;                  // pool2g grid

    float* f0 = (float*)d_ws;
    size_t o = 0;
    float*    xl       = f0 + o; o += (size_t)n;                  // fallback only
    float*    xr       = f0 + o; o += (size_t)n;                  // fallback only
    float2*   sA       = (float2*)(f0 + o); o += 2 * (size_t)n;
    float*    B        = f0 + o; o += (size_t)n;
    float*    logits   = f0 + o; o += (size_t)n;
    o = (o + 3) & ~(size_t)3;
    float2*   NS       = (float2*)(f0 + o); o += 2 * (size_t)n;   // fallback NS / fallback partials
    float4*   partialF = (float4*)NS;
    unsigned* stampW   = (unsigned*)(f0 + o); o += (size_t)nW;
    unsigned char* stamp = (unsigned char*)stampW;
    unsigned* pooled_u = (unsigned*)(f0 + o); o += 256;
    unsigned* sc       = (unsigned*)(f0 + o); o += 64;
    unsigned* gBase    = (unsigned*)(f0 + o); o += MAXBINS;
    unsigned* gCursor  = (unsigned*)(f0 + o); o += MAXBINS;
    unsigned* gHist    = (unsigned*)(f0 + o); o += MAXBINS;
    o = (o + 3) & ~(size_t)3;
    float4*   gABpart  = (float4*)(f0 + o); o += 4 * (size_t)gP;
    o = (o + 15) & ~(size_t)15;                                   // 64B align
    unsigned* recs     = (unsigned*)(f0 + o);
    float4*   partialT = (float4*)recs;                            // reuse recs after BFS
    float4*   partial2 = (float4*)(recs + (size_t)POOLB * 256);    // after partialT

    size_t capWords = (size_t)E + (size_t)nbins * (15u * (size_t)nBlkScat + 16u);
    size_t poolWords = (size_t)POOLB * 256 + (size_t)POOL2B * 256;
    if (poolWords > capWords) capWords = poolWords;
    size_t need_bytes = (o + capWords) * sizeof(float);
    const bool sorted_ok = (ws_size >= need_bytes) && (nbins <= MAXBINS) &&
                           (E % 4 == 0) && (n <= (1 << 17));

    float* out = (float*)d_out;

    if (sorted_ok) {
        k_pre<<<gP, Bk, 0, stream>>>(x, w_l, w_r, pos, w_e, sA, B, gABpart,
                                     stampW, gHist, sc, n, nW);
        k_hist<<<512, Bk, 0, stream>>>((const int4*)dst, E4, nbins, gHist);
        k_scan2<<<1, Bk, 0, stream>>>(gABpart, gP, gHist, gBase, gCursor,
                                      nbins, nBlkScat, sc, att);
        k_scatter<<<nBlkScat, 512, 0, stream>>>((const int4*)src, (const int4*)dst,
                                                gCursor, recs, E4, nbins);
        k_binsum<<<nbins, Bk, 0, stream>>>((const uint4*)recs, gBase, gCursor, sA, B,
                                           att, bias, logits, sc, n);
        k_sumarg<<<gN, Bk, 0, stream>>>(logits, sc, n);
        k_score<<<gN, Bk, 0, stream>>>(logits, sc, out, stamp, n);
        for (int t = 1; t <= 5; ++t) {
            k_bfs_stamp<<<gE4, Bk, 0, stream>>>((const int4*)src, (const int4*)dst,
                                                stamp, E4, t);
        }
        k_pool1<<<POOLB, Bk, 0, stream>>>(x, stamp, partialT, n);
        k_pool2g<<<POOL2B, Bk, 0, stream>>>(partialT, POOLB, partial2, sc, out, n);
    } else {
        k_init<<<gN, Bk, 0, stream>>>(NS, stampW, nW, pooled_u, sc, n);
        k_dots<<<gD, Bk, 0, stream>>>(x, w_l, w_r, xl, xr, n);
        k_ab<<<gN, Bk, 0, stream>>>(xl, xr, pos, w_e, sA, B, sc, n);
        k_scanM<<<1, 64, 0, stream>>>(sc, att);
        k_edge_sum<<<gE, Bk, 0, stream>>>(src, dst, sA, B, att, sc, NS, E);
        k_logits<<<gN, Bk, 0, stream>>>(NS, bias, logits, sc, n);
        k_sumarg<<<gN, Bk, 0, stream>>>(logits, sc, n);
        k_score<<<gN, Bk, 0, stream>>>(logits, sc, out, stamp, n);
        for (int t = 1; t <= 5; ++t) {
            k_bfs_stamp<<<gE4, Bk, 0, stream>>>((const int4*)src, (const int4*)dst,
                                                stamp, E4, t);
        }
        int nblk1 = (int)((2 * (size_t)n) / 256);
        if (nblk1 > 768) nblk1 = 768;
        if (nblk1 < 1) nblk1 = 1;
        k_pool1<<<nblk1, Bk, 0, stream>>>(x, stamp, partialF, n);
        k_pool2<<<16, Bk, 0, stream>>>(partialF, nblk1, pooled_u);
        k_poolwrite<<<1, Bk, 0, stream>>>(pooled_u, out, n);
    }
}